// Round 6
// baseline (133.140 us; speedup 1.0000x reference)
//
#include <hip/hip_runtime.h>

#define SS 160
#define DD 256
#define BB 8
#define NPAIR 12720            // S*(S-1)/2
#define M_TOT (BB * SS)        // 1280
#define TOTROWS (BB * NPAIR)   // 101760
#define NWAVES 8192            // 2048 blocks x 4 waves = 8 waves/SIMD device-wide

typedef float nfloat4 __attribute__((ext_vector_type(4)));   // native vec: ok for nontemporal builtins

// ---------------------------------------------------------------------------
// Kernel 1 (v4): fused double GEMM. BM=32, BN=64, BK=64 -> 4 k-iters, 8
// barriers. Grid (8,40)=320 blocks. Each thread: 2 rows x 4 cols.
//   ya[m][e] = x[m][:] @ W[:256][e] + bias[e]
//   yb[m][e] = x[m][:] @ W[256:][e]
// ---------------------------------------------------------------------------
__global__ __launch_bounds__(256) void gemm_kernel(const float* __restrict__ x,
                                                   const float* __restrict__ W,
                                                   const float* __restrict__ bias,
                                                   float* __restrict__ y) {
    const int BM = 32, BN = 64, BK = 64;
    __shared__ float As[BK][BM + 1];   // transposed: As[k][m], +1 pad
    __shared__ float Bs[BK][BN];

    const int n0 = blockIdx.x * BN;          // 0..511 step 64 (stays in one half)
    const int m0 = blockIdx.y * BM;
    const int half = (n0 >= DD) ? 1 : 0;
    const float* Wbase = W + (half ? DD * DD : 0);
    const int ncol0 = n0 - (half ? DD : 0);

    const int tid = threadIdx.x;
    const int tx = tid & 15;            // col group: cols 4*tx..4*tx+3
    const int ty = tid >> 4;            // rows ty and ty+16

    // global loader mapping
    const int ar = tid >> 3;            // A row 0..31
    const int ac = (tid & 7) << 3;      // A k-offset 0..56 step 8 (loads 8 floats)
    const int bk = tid >> 2;            // B k-row 0..63
    const int bc = (tid & 3) << 4;      // B col {0,16,32,48} (loads 16 floats)

    float acc0[4] = {0.f, 0.f, 0.f, 0.f};
    float acc1[4] = {0.f, 0.f, 0.f, 0.f};

    for (int k0 = 0; k0 < DD; k0 += BK) {
        float4 a0 = *(const float4*)(x + (m0 + ar) * DD + k0 + ac);
        float4 a1 = *(const float4*)(x + (m0 + ar) * DD + k0 + ac + 4);
        float4 b0 = *(const float4*)(Wbase + (k0 + bk) * DD + ncol0 + bc);
        float4 b1 = *(const float4*)(Wbase + (k0 + bk) * DD + ncol0 + bc + 4);
        float4 b2 = *(const float4*)(Wbase + (k0 + bk) * DD + ncol0 + bc + 8);
        float4 b3 = *(const float4*)(Wbase + (k0 + bk) * DD + ncol0 + bc + 12);
        __syncthreads();                         // previous tile's reads done
        As[ac + 0][ar] = a0.x; As[ac + 1][ar] = a0.y;
        As[ac + 2][ar] = a0.z; As[ac + 3][ar] = a0.w;
        As[ac + 4][ar] = a1.x; As[ac + 5][ar] = a1.y;
        As[ac + 6][ar] = a1.z; As[ac + 7][ar] = a1.w;
        *(float4*)(&Bs[bk][bc])      = b0;
        *(float4*)(&Bs[bk][bc + 4])  = b1;
        *(float4*)(&Bs[bk][bc + 8])  = b2;
        *(float4*)(&Bs[bk][bc + 12]) = b3;
        __syncthreads();
#pragma unroll 16
        for (int kk = 0; kk < BK; ++kk) {
            float a0s = As[kk][ty];
            float a1s = As[kk][ty + 16];
            float4 bv = *(const float4*)(&Bs[kk][tx << 2]);
            acc0[0] += a0s * bv.x; acc0[1] += a0s * bv.y;
            acc0[2] += a0s * bv.z; acc0[3] += a0s * bv.w;
            acc1[0] += a1s * bv.x; acc1[1] += a1s * bv.y;
            acc1[2] += a1s * bv.z; acc1[3] += a1s * bv.w;
        }
    }

    float4 bias4 = make_float4(0.f, 0.f, 0.f, 0.f);
    if (!half) bias4 = *(const float4*)(bias + ncol0 + (tx << 2));   // bias folded into ya only

    float* yout = y + (half ? M_TOT * DD : 0);
    float4 r0, r1;
    r0.x = acc0[0] + bias4.x; r0.y = acc0[1] + bias4.y;
    r0.z = acc0[2] + bias4.z; r0.w = acc0[3] + bias4.w;
    r1.x = acc1[0] + bias4.x; r1.y = acc1[1] + bias4.y;
    r1.z = acc1[2] + bias4.z; r1.w = acc1[3] + bias4.w;
    *(float4*)(yout + (m0 + ty) * DD + ncol0 + (tx << 2))      = r0;
    *(float4*)(yout + (m0 + ty + 16) * DD + ncol0 + (tx << 2)) = r1;
}

// ---------------------------------------------------------------------------
// Kernel 2 (v5): balanced pair expansion, run-decomposed + 4x unrolled +
// NONTEMPORAL output stores (nt flag: keep the 104 MB write-once stream from
// thrashing L2, so ya/yb stay L2-resident). Uses clang native vec type for
// the builtin.
// ---------------------------------------------------------------------------
__global__ __launch_bounds__(256) void expand_kernel(const float* __restrict__ y,
                                                     float* __restrict__ out) {
    const int gw   = (blockIdx.x << 2) + (threadIdx.x >> 6);   // 0..NWAVES-1
    const int lane = threadIdx.x & 63;

    int r0 = (int)(((long long)gw * TOTROWS) / NWAVES);
    int r1 = (int)(((long long)(gw + 1) * TOTROWS) / NWAVES);

    int b = (unsigned)r0 / NPAIR;
    int p = r0 - b * NPAIR;

    // invert p -> (i,j): offset(i) = i*(2S-1-i)/2, j = i+1 + (p - offset(i))
    float disc = sqrtf((float)(101761 - 8 * p));     // (2S-1)^2 = 101761
    int i = (int)((319.0f - disc) * 0.5f);
    if (i < 0) i = 0;
    if (i > SS - 2) i = SS - 2;
    while (i > 0 && (i * (2 * SS - 1 - i)) / 2 > p) --i;
    while (((i + 1) * (2 * SS - 2 - i)) / 2 <= p) ++i;
    int j = i + 1 + p - (i * (2 * SS - 1 - i)) / 2;

    const nfloat4* ya4 = (const nfloat4*)y;
    const nfloat4* yb4 = (const nfloat4*)(y + M_TOT * DD);
    nfloat4* po = (nfloat4*)out + ((long long)r0 << 6) + lane;

    int r = r0;
    while (r < r1) {
        int run = r1 - r;
        int jrem = SS - j;
        if (jrem < run) run = jrem;                 // rows with consecutive j

        const nfloat4 va = ya4[((b * SS + i) << 6) + lane];
        const nfloat4* pb = yb4 + ((b * SS + j) << 6) + lane;

        int k = 0;
        for (; k + 4 <= run; k += 4) {              // 4 loads in flight
            nfloat4 v0 = pb[0];
            nfloat4 v1 = pb[64];
            nfloat4 v2 = pb[128];
            nfloat4 v3 = pb[192];
            __builtin_nontemporal_store(va + v0, po);
            __builtin_nontemporal_store(va + v1, po + 64);
            __builtin_nontemporal_store(va + v2, po + 128);
            __builtin_nontemporal_store(va + v3, po + 192);
            pb += 256;
            po += 256;
        }
        for (; k < run; ++k) {
            nfloat4 vb = *pb;
            __builtin_nontemporal_store(va + vb, po);
            pb += 64;
            po += 64;
        }

        r += run;
        j += run;
        if (j == SS) {                              // advance to next i (wave-uniform)
            ++i;
            if (i == SS - 1) { ++b; i = 0; }
            j = i + 1;
        }
    }
}

extern "C" void kernel_launch(void* const* d_in, const int* in_sizes, int n_in,
                              void* d_out, int out_size, void* d_ws, size_t ws_size,
                              hipStream_t stream) {
    const float* x    = (const float*)d_in[0];   // (8,160,256)
    const float* W    = (const float*)d_in[1];   // (512,256)
    const float* bias = (const float*)d_in[2];   // (256,)
    float* y   = (float*)d_ws;                   // ya[1280*256] then yb[1280*256]
    float* out = (float*)d_out;                  // (8,12720,256)

    dim3 gemm_grid(512 / 64, 1280 / 32);         // 8 x 40 = 320 blocks
    gemm_kernel<<<gemm_grid, 256, 0, stream>>>(x, W, bias, y);

    expand_kernel<<<NWAVES / 4, 256, 0, stream>>>(y, out);
}